// Round 1
// baseline (382.969 us; speedup 1.0000x reference)
//
#include <hip/hip_runtime.h>

#define B 2
#define N_RES 2048
#define N_ATOM 16384
#define C_S 384
#define C_OUT 50

// Kernel 1: proj[b,r,o] = bias[o] + sum_c s[b,r,c] * W[o,c]
// One 64-thread block per (b, res). s-row staged in LDS (broadcast reads),
// W rows read per-lane as float4 (77 KB total -> hot in L2 after first blocks).
__global__ __launch_bounds__(64) void proj_kernel(const float* __restrict__ s,
                                                  const float* __restrict__ W,
                                                  const float* __restrict__ bias,
                                                  float* __restrict__ proj) {
    int br = blockIdx.x;            // 0 .. B*N_RES-1
    int lane = threadIdx.x;         // 0..63
    __shared__ float srow[C_S];
    const float* sp = s + (size_t)br * C_S;
    for (int i = lane; i < C_S; i += 64) srow[i] = sp[i];
    __syncthreads();
    if (lane < C_OUT) {
        const float* wp = W + lane * C_S;
        float acc = bias[lane];
        #pragma unroll 4
        for (int c = 0; c < C_S; c += 4) {
            float4 w4 = *(const float4*)(wp + c);
            acc += srow[c] * w4.x + srow[c + 1] * w4.y
                 + srow[c + 2] * w4.z + srow[c + 3] * w4.w;
        }
        proj[(size_t)br * C_OUT + lane] = acc;
    }
}

// Kernel 2: one wave per atom. Scan the one-hot row (2048 floats) in rounds of
// 256 floats (float4/lane), early-exit via ballot when the 1.0 is found, then
// lanes 0..49 copy proj[b, r, :] to out[b, a, :].
__global__ __launch_bounds__(256) void gather_kernel(const float* __restrict__ onehot,
                                                     const float* __restrict__ proj,
                                                     float* __restrict__ out) {
    int lane = threadIdx.x & 63;
    int w = (blockIdx.x << 2) + (threadIdx.x >> 6);   // atom id over B*N_ATOM
    const float* row = onehot + (size_t)w * N_RES;

    int r = 0;
    #pragma unroll 1
    for (int iter = 0; iter < N_RES / 256; ++iter) {
        int base = iter * 256 + lane * 4;
        float4 v = *(const float4*)(row + base);
        int j = -1;
        if (v.x != 0.f) j = 0;
        else if (v.y != 0.f) j = 1;
        else if (v.z != 0.f) j = 2;
        else if (v.w != 0.f) j = 3;
        unsigned long long mask = __ballot(j >= 0);
        if (mask) {                                   // wave-uniform
            int src = (int)__ffsll(mask) - 1;
            r = __shfl(base + j, src);
            break;
        }
    }

    int b = w >> 14;                                  // / N_ATOM
    if (lane < C_OUT) {
        out[(size_t)w * C_OUT + lane] = proj[((size_t)b * N_RES + r) * C_OUT + lane];
    }
}

extern "C" void kernel_launch(void* const* d_in, const int* in_sizes, int n_in,
                              void* d_out, int out_size, void* d_ws, size_t ws_size,
                              hipStream_t stream) {
    const float* s      = (const float*)d_in[0];   // [B, N_RES, C_S]
    const float* onehot = (const float*)d_in[1];   // [B, N_ATOM, N_RES]
    const float* W      = (const float*)d_in[2];   // [C_OUT, C_S]
    const float* bias   = (const float*)d_in[3];   // [C_OUT]
    float* out  = (float*)d_out;                   // [B, N_ATOM, C_OUT]
    float* proj = (float*)d_ws;                    // B*N_RES*C_OUT floats = 819200 B

    proj_kernel<<<B * N_RES, 64, 0, stream>>>(s, W, bias, proj);
    gather_kernel<<<(B * N_ATOM) / 4, 256, 0, stream>>>(onehot, proj, out);
}

// Round 3
// 381.039 us; speedup vs baseline: 1.0051x; 1.0051x over previous
//
#include <hip/hip_runtime.h>

#define B 2
#define N_RES 2048
#define N_ATOM 16384
#define C_S 384
#define C_OUT 50

#define SCAN_BLOCKS 8192   // 4 waves/block -> 32768 atoms (one wave per atom)
#define PROJ_BLOCKS 1024   // 4 waves/block -> 4096 residues (one wave per residue)

typedef float nfloat4 __attribute__((ext_vector_type(4)));  // native vec for nontemporal builtin

// K1: scan blocks find each atom's residue index (early-exit one-hot scan,
// HBM-bound); proj blocks compute proj[b,r,o] = bias[o] + s[b,r,:]·W[o,:]
// (L2-bound on W re-reads). Disjoint pipes -> they overlap.
__global__ __launch_bounds__(256) void fused_scan_proj(const float* __restrict__ s,
                                                       const float* __restrict__ W,
                                                       const float* __restrict__ bias,
                                                       const float* __restrict__ onehot,
                                                       float* __restrict__ proj,
                                                       int* __restrict__ idx) {
    __shared__ float srow[4][C_S];
    int wave = threadIdx.x >> 6;
    int lane = threadIdx.x & 63;

    if (blockIdx.x < SCAN_BLOCKS) {
        // -------- index scan: one wave per atom --------
        int a = (blockIdx.x << 2) + wave;              // 0 .. B*N_ATOM-1
        const float* row = onehot + (size_t)a * N_RES;
        int r = 0;
        #pragma unroll 1
        for (int iter = 0; iter < N_RES / 256; ++iter) {
            int base = iter * 256 + (lane << 2);
            nfloat4 v = __builtin_nontemporal_load((const nfloat4*)(row + base));
            int j = -1;
            if (v.x != 0.f) j = 0;
            else if (v.y != 0.f) j = 1;
            else if (v.z != 0.f) j = 2;
            else if (v.w != 0.f) j = 3;
            unsigned long long mask = __ballot(j >= 0);
            if (mask) {                                // wave-uniform
                int src = (int)__ffsll(mask) - 1;
                r = __shfl(base + j, src);
                break;
            }
        }
        if (lane == 0) idx[a] = r;
    } else {
        // -------- projection: one wave per residue --------
        int rr = ((blockIdx.x - SCAN_BLOCKS) << 2) + wave;   // 0 .. B*N_RES-1
        const float4* sp = (const float4*)(s + (size_t)rr * C_S);
        float4* srp = (float4*)srow[wave];
        for (int i = lane; i < C_S / 4; i += 64) srp[i] = sp[i];
        __syncthreads();   // block-uniform branch: all 256 threads reach this
        if (lane < C_OUT) {
            const float* wp = W + lane * C_S;
            float acc = bias[lane];
            #pragma unroll 4
            for (int c = 0; c < C_S; c += 4) {
                float4 w4 = *(const float4*)(wp + c);
                acc += srow[wave][c]     * w4.x + srow[wave][c + 1] * w4.y
                     + srow[wave][c + 2] * w4.z + srow[wave][c + 3] * w4.w;
            }
            proj[(size_t)rr * C_OUT + lane] = acc;
        }
    }
}

// K2: one wave per atom: out[a, :] = proj[b, idx[a], :]  (proj is L2-hot)
__global__ __launch_bounds__(256) void gather_kernel(const int* __restrict__ idx,
                                                     const float* __restrict__ proj,
                                                     float* __restrict__ out) {
    int wave = threadIdx.x >> 6;
    int lane = threadIdx.x & 63;
    int a = (blockIdx.x << 2) + wave;                  // 0 .. B*N_ATOM-1
    int r = idx[a];                                    // broadcast load
    int b = a >> 14;                                   // / N_ATOM
    if (lane < C_OUT) {
        out[(size_t)a * C_OUT + lane] = proj[((size_t)b * N_RES + r) * C_OUT + lane];
    }
}

extern "C" void kernel_launch(void* const* d_in, const int* in_sizes, int n_in,
                              void* d_out, int out_size, void* d_ws, size_t ws_size,
                              hipStream_t stream) {
    const float* s      = (const float*)d_in[0];   // [B, N_RES, C_S]
    const float* onehot = (const float*)d_in[1];   // [B, N_ATOM, N_RES]
    const float* W      = (const float*)d_in[2];   // [C_OUT, C_S]
    const float* bias   = (const float*)d_in[3];   // [C_OUT]
    float* out  = (float*)d_out;                   // [B, N_ATOM, C_OUT]

    float* proj = (float*)d_ws;                            // 819200 B
    int*   idx  = (int*)((char*)d_ws + (1 << 20));         // 128 KiB at 1 MiB offset

    fused_scan_proj<<<SCAN_BLOCKS + PROJ_BLOCKS, 256, 0, stream>>>(s, W, bias, onehot,
                                                                   proj, idx);
    gather_kernel<<<SCAN_BLOCKS, 256, 0, stream>>>(idx, proj, out);
}

// Round 4
// 379.020 us; speedup vs baseline: 1.0104x; 1.0053x over previous
//
#include <hip/hip_runtime.h>

#define B 2
#define N_RES 2048
#define N_ATOM 16384
#define C_S 384
#define C_OUT 50

#define PROJ_BLOCKS 1024                        // 4 waves/block -> 4096 residues
#define SCAN_BLOCKS 8192
#define TOTAL_F4 (B * N_ATOM * N_RES / 4)       // 16777216 float4 elements
#define SCAN_STRIDE (SCAN_BLOCKS * 256)         // 2097152 threads in scan portion
#define SCAN_ITERS (TOTAL_F4 / SCAN_STRIDE)     // 8

typedef float nfloat4 __attribute__((ext_vector_type(4)));

// Blocks [0, PROJ_BLOCKS): proj[b,r,o] = bias[o] + s[b,r,:]·W[o,:]  (L2-bound).
// Blocks [PROJ_BLOCKS, +SCAN_BLOCKS): streaming one-hot scan — 8 independent
// nontemporal float4 loads per lane (no dependent-chain latency), conditional
// scatter of the residue index. Proj blocks first so they overlap early scan.
__global__ __launch_bounds__(256) void fused_scan_proj(const float* __restrict__ s,
                                                       const float* __restrict__ W,
                                                       const float* __restrict__ bias,
                                                       const float* __restrict__ onehot,
                                                       float* __restrict__ proj,
                                                       int* __restrict__ idx) {
    __shared__ float srow[4][C_S];
    int wave = threadIdx.x >> 6;
    int lane = threadIdx.x & 63;

    if (blockIdx.x >= PROJ_BLOCKS) {
        // -------- streaming scan: all loads independent & in flight --------
        size_t t0 = (size_t)(blockIdx.x - PROJ_BLOCKS) * 256 + threadIdx.x;
        nfloat4 v[SCAN_ITERS];
        #pragma unroll
        for (int k = 0; k < SCAN_ITERS; ++k)
            v[k] = __builtin_nontemporal_load(
                       (const nfloat4*)onehot + t0 + (size_t)k * SCAN_STRIDE);
        #pragma unroll
        for (int k = 0; k < SCAN_ITERS; ++k) {
            nfloat4 x = v[k];
            if (x.x != 0.f || x.y != 0.f || x.z != 0.f || x.w != 0.f) {
                size_t e = (t0 + (size_t)k * SCAN_STRIDE) << 2;      // flat elem idx
                int j = (x.x != 0.f) ? 0 : (x.y != 0.f) ? 1 : (x.z != 0.f) ? 2 : 3;
                size_t ee = e + j;
                idx[ee >> 11] = (int)(ee & (N_RES - 1));             // idx[a] = r
            }
        }
    } else {
        // -------- projection: one wave per residue --------
        int rr = (blockIdx.x << 2) + wave;                 // 0 .. B*N_RES-1
        const float4* sp = (const float4*)(s + (size_t)rr * C_S);
        float4* srp = (float4*)srow[wave];
        for (int i = lane; i < C_S / 4; i += 64) srp[i] = sp[i];
        __syncthreads();   // branch is block-uniform: all 256 threads reach this
        if (lane < C_OUT) {
            const float* wp = W + lane * C_S;
            float acc = bias[lane];
            #pragma unroll 4
            for (int c = 0; c < C_S; c += 4) {
                float4 w4 = *(const float4*)(wp + c);
                acc += srow[wave][c]     * w4.x + srow[wave][c + 1] * w4.y
                     + srow[wave][c + 2] * w4.z + srow[wave][c + 3] * w4.w;
            }
            proj[(size_t)rr * C_OUT + lane] = acc;
        }
    }
}

// K2: one wave per atom: out[a, :] = proj[b, idx[a], :]  (proj is L2-hot)
__global__ __launch_bounds__(256) void gather_kernel(const int* __restrict__ idx,
                                                     const float* __restrict__ proj,
                                                     float* __restrict__ out) {
    int wave = threadIdx.x >> 6;
    int lane = threadIdx.x & 63;
    int a = (blockIdx.x << 2) + wave;                  // 0 .. B*N_ATOM-1
    int r = idx[a];                                    // broadcast load
    int b = a >> 14;                                   // / N_ATOM
    if (lane < C_OUT) {
        out[(size_t)a * C_OUT + lane] = proj[((size_t)b * N_RES + r) * C_OUT + lane];
    }
}

extern "C" void kernel_launch(void* const* d_in, const int* in_sizes, int n_in,
                              void* d_out, int out_size, void* d_ws, size_t ws_size,
                              hipStream_t stream) {
    const float* s      = (const float*)d_in[0];   // [B, N_RES, C_S]
    const float* onehot = (const float*)d_in[1];   // [B, N_ATOM, N_RES]
    const float* W      = (const float*)d_in[2];   // [C_OUT, C_S]
    const float* bias   = (const float*)d_in[3];   // [C_OUT]
    float* out  = (float*)d_out;                   // [B, N_ATOM, C_OUT]

    float* proj = (float*)d_ws;                            // 819200 B
    int*   idx  = (int*)((char*)d_ws + (1 << 20));         // 128 KiB at 1 MiB offset

    fused_scan_proj<<<PROJ_BLOCKS + SCAN_BLOCKS, 256, 0, stream>>>(s, W, bias, onehot,
                                                                   proj, idx);
    gather_kernel<<<(B * N_ATOM) / 4, 256, 0, stream>>>(idx, proj, out);
}